// Round 5
// baseline (972.845 us; speedup 1.0000x reference)
//
#include <hip/hip_runtime.h>

typedef unsigned short u16;
typedef unsigned int u32;

#define T_ 768
#define D_ 24
#define S_ 576
#define Q_ 32
#define K_ 128
#define CA_ 128
#define CP_ 16
#define CT_ 384
#define H_ 4
#define DH_ 32
#define SQ_ (S_*Q_)
#define SK_ (S_*K_)

__device__ __forceinline__ float b2f(u16 u){ return __uint_as_float(((u32)u)<<16); }
__device__ __forceinline__ u16 f2b(float f){ u32 x=__float_as_uint(f); return (u16)((x + 0x7fffu + ((x>>16)&1u))>>16); }

// ---- N1: per-atom conditioning gathered to query slots; also qrp/quid ----
__global__ __launch_bounds__(128) void n_qsc(
    const float* __restrict__ pos, const float* __restrict__ rmask, const float* __restrict__ charge,
    const float* __restrict__ amask, const int* __restrict__ elem, const int* __restrict__ chars,
    const int* __restrict__ uid, const int* __restrict__ t2q,
    const float* __restrict__ w_pos, const float* __restrict__ w_mask, const float* __restrict__ w_elem,
    const float* __restrict__ w_chg, const float* __restrict__ w_name,
    float* __restrict__ qsc, float* __restrict__ qmask, float* __restrict__ qrp, int* __restrict__ quid,
    float* __restrict__ out_qsc, float* __restrict__ out_qmask)
{
  int slot = blockIdx.x, ch = threadIdx.x;
  int a = t2q[slot];
  float p0 = pos[a*3+0], p1 = pos[a*3+1], p2 = pos[a*3+2];
  float m  = rmask[a];
  float cg = asinhf(charge[a]);
  int e  = elem[a];
  int c0 = chars[a*4+0], c1 = chars[a*4+1], c2 = chars[a*4+2], c3 = chars[a*4+3];
  float v = p0*w_pos[0*CA_+ch] + p1*w_pos[1*CA_+ch] + p2*w_pos[2*CA_+ch];
  v += m * w_mask[ch];
  v += w_elem[e*CA_+ch];
  v += cg * w_chg[ch];
  v += w_name[(0*64+c0)*CA_+ch] + w_name[(1*64+c1)*CA_+ch]
     + w_name[(2*64+c2)*CA_+ch] + w_name[(3*64+c3)*CA_+ch];
  v *= m;
  qsc[(size_t)slot*CA_+ch] = v;
  out_qsc[(size_t)slot*CA_+ch] = v;
  if (ch < 3) qrp[slot*3+ch] = pos[a*3+ch];
  if (ch == 0){
    float am = amask[a];
    qmask[slot] = am;
    out_qmask[slot] = am;
    quid[slot] = uid[a];
  }
}

// ---- N2: key-space gathers (ksc, kmask outputs; krp; kuid = uid[q2k] DIRECT) ----
__global__ __launch_bounds__(128) void n_keys(
    const float* __restrict__ qsc, const float* __restrict__ qmask, const float* __restrict__ qrp,
    const int* __restrict__ uid, const int* __restrict__ q2k,
    float* __restrict__ krp, int* __restrict__ kuid,
    float* __restrict__ out_ksc, float* __restrict__ out_kmask)
{
  int sk = blockIdx.x, ch = threadIdx.x;
  int j = q2k[sk];
  out_ksc[(size_t)sk*CA_+ch] = qsc[(size_t)j*CA_+ch];
  if (ch < 3) krp[sk*3+ch] = qrp[j*3+ch];
  if (ch == 0){
    out_kmask[sk] = qmask[j];
    // Reference: keys_uid = ref_space_uid.flat[q2k_idx]  (direct, NOT via t2q)
    kuid[sk] = uid[j];
  }
}

// ---- N3: generic 128->128 row-linear  Y[r][c] = sum_i X[r][i] * W[i][c] * scale ----
__global__ __launch_bounds__(128) void n_proj128(
    const float* __restrict__ X, const float* __restrict__ W, float* __restrict__ Y, float scale)
{
  int slot = blockIdx.x, c = threadIdx.x;
  float acc = 0.f;
  for (int i = 0; i < CA_; ++i)
    acc += X[(size_t)slot*CA_+i] * W[i*CA_+c];
  Y[(size_t)slot*CA_+c] = acc * scale;
}

// ---- N4: 128->16 row-linear with relu on input ----
__global__ __launch_bounds__(128) void n_proj16(
    const float* __restrict__ X, const float* __restrict__ W, float* __restrict__ Y)
{
  int row = blockIdx.x*8 + (threadIdx.x >> 4);
  int c = threadIdx.x & 15;
  float acc = 0.f;
  for (int i = 0; i < CA_; ++i)
    acc += fmaxf(X[(size_t)row*CA_+i], 0.f) * W[i*CP_+c];
  Y[(size_t)row*CP_+c] = acc;
}

// ---- N5: pair conditioning + 3-layer MLP + bias. One block per (s,q), thread = k ----
__global__ __launch_bounds__(128) void n_pair(
    const int* __restrict__ q2k, const float* __restrict__ rowproj, const float* __restrict__ colproj,
    const float* __restrict__ qrp, const int* __restrict__ quid,
    const float* __restrict__ krp, const int* __restrict__ kuid,
    const float* __restrict__ w1, const float* __restrict__ w2, const float* __restrict__ w3,
    const float* __restrict__ wpo, const float* __restrict__ wpd, const float* __restrict__ wpv,
    const float* __restrict__ wb,
    float* __restrict__ out_pair, u16* __restrict__ bias_ws)
{
  __shared__ float w1s[256], w2s[256], w3s[256], wbs[64], wpos[48], wpds[16], wpvs[16];
  int tid = threadIdx.x;
  for (int e = tid; e < 256; e += 128){ w1s[e] = w1[e]; w2s[e] = w2[e]; w3s[e] = w3[e]; }
  if (tid < 64) wbs[tid] = wb[tid];
  if (tid < 48) wpos[tid] = wpo[tid];
  if (tid < 16){ wpds[tid] = wpd[tid]; wpvs[tid] = wpv[tid]; }
  __syncthreads();

  int sq = blockIdx.x;          // s*Q + q
  int s  = sq >> 5;
  int k  = tid;
  int sk = s*K_ + k;
  int j  = q2k[sk];

  float p[16];
  {
    float ox = qrp[sq*3+0] - krp[sk*3+0];
    float oy = qrp[sq*3+1] - krp[sk*3+1];
    float oz = qrp[sq*3+2] - krp[sk*3+2];
    float vf = (quid[sq] == kuid[sk]) ? 1.f : 0.f;
    float invd = vf / (1.f + ox*ox + oy*oy + oz*oz);
    #pragma unroll
    for (int c = 0; c < 16; ++c)
      p[c] = rowproj[(size_t)sq*CP_+c] + colproj[(size_t)j*CP_+c]
           + vf*(ox*wpos[c] + oy*wpos[16+c] + oz*wpos[32+c])
           + invd*wpds[c] + vf*wpvs[c];
  }
  float y[16];
  #pragma unroll
  for (int c = 0; c < 16; ++c) y[c] = 0.f;
  for (int i = 0; i < 16; ++i){
    float u = fmaxf(p[i], 0.f);
    #pragma unroll
    for (int c = 0; c < 16; ++c) y[c] += u * w1s[i*16+c];
  }
  float z[16];
  #pragma unroll
  for (int c = 0; c < 16; ++c) z[c] = 0.f;
  for (int i = 0; i < 16; ++i){
    float u = fmaxf(y[i], 0.f);
    #pragma unroll
    for (int c = 0; c < 16; ++c) z[c] += u * w2s[i*16+c];
  }
  for (int i = 0; i < 16; ++i){
    float u = fmaxf(z[i], 0.f);
    #pragma unroll
    for (int c = 0; c < 16; ++c) p[c] += u * w3s[i*16+c];
  }
  float b[4] = {0.f, 0.f, 0.f, 0.f};
  for (int c = 0; c < 16; ++c){
    #pragma unroll
    for (int h = 0; h < 4; ++h) b[h] += p[c] * wbs[c*4+h];
  }
  size_t rg = (size_t)sq*K_ + k;     // = s*4096 + q*128 + k
  for (int c = 0; c < 16; ++c) out_pair[rg*16+c] = p[c];
  for (int h = 0; h < 4; ++h)  bias_ws[rg*4+h] = f2b(b[h]);
}

// ---- N6: attention. One 64-thread block per (s,q,h) ----
__global__ __launch_bounds__(64) void n_attn(
    const float* __restrict__ Qp, const float* __restrict__ Kp, const float* __restrict__ Vp,
    const float* __restrict__ qmask, const u16* __restrict__ bias_ws, const int* __restrict__ q2k,
    float* __restrict__ O)
{
  __shared__ float attn[128];
  __shared__ int jbuf[128];
  int b = blockIdx.x;
  int sq = b >> 2, h = b & 3;
  int s = sq >> 5;
  int l = threadIdx.x;
  int base = s*K_;

  float lo[2];
  #pragma unroll
  for (int t = 0; t < 2; ++t){
    int k = l + t*64;
    int j = q2k[base+k];
    jbuf[k] = j;
    float acc = 0.f;
    for (int d = 0; d < DH_; ++d)
      acc += Qp[(size_t)sq*CA_ + h*DH_ + d] * Kp[(size_t)j*CA_ + h*DH_ + d];
    acc += b2f(bias_ws[((size_t)sq*K_ + k)*4 + h]);
    lo[t] = (qmask[j] > 0.f) ? acc : -1e9f;
  }
  float m = fmaxf(lo[0], lo[1]);
  #pragma unroll
  for (int off = 32; off >= 1; off >>= 1) m = fmaxf(m, __shfl_xor(m, off, 64));
  float e0 = __expf(lo[0]-m), e1 = __expf(lo[1]-m);
  float sm = e0 + e1;
  #pragma unroll
  for (int off = 32; off >= 1; off >>= 1) sm += __shfl_xor(sm, off, 64);
  float inv = 1.f / sm;
  attn[l] = e0*inv;
  attn[64+l] = e1*inv;
  __syncthreads();
  if (l < DH_){
    float acc = 0.f;
    for (int k = 0; k < K_; ++k)
      acc += attn[k] * Vp[(size_t)jbuf[k]*CA_ + h*DH_ + l];
    O[(size_t)sq*CA_ + h*DH_ + l] = acc;
  }
}

// ---- N7: queries_act = (qsc + O @ wo) * qmask ----
__global__ __launch_bounds__(128) void n_qact(
    const float* __restrict__ qsc, const float* __restrict__ O, const float* __restrict__ qmask,
    const float* __restrict__ wo, float* __restrict__ qact, float* __restrict__ out_skip)
{
  int slot = blockIdx.x, c = threadIdx.x;
  float acc = qsc[(size_t)slot*CA_+c];
  for (int i = 0; i < CA_; ++i)
    acc += O[(size_t)slot*CA_+i] * wo[i*CA_+c];
  acc *= qmask[slot];
  qact[(size_t)slot*CA_+c] = acc;
  out_skip[(size_t)slot*CA_+c] = acc;
}

// ---- N8: proj + gather + masked mean ----
__global__ __launch_bounds__(384) void n_tok(
    const float* __restrict__ qact, const int* __restrict__ q2t, const float* __restrict__ amask,
    const float* __restrict__ wp, float* __restrict__ out_tok)
{
  int t = blockIdx.x, ct = threadIdx.x;
  float num = 0.f, den = 1e-10f;
  for (int d = 0; d < D_; ++d){
    int j = q2t[t*D_+d];
    float a = 0.f;
    for (int i = 0; i < CA_; ++i)
      a += qact[(size_t)j*CA_+i] * wp[i*CT_+ct];
    float am = amask[t*D_+d];
    num += am * fmaxf(a, 0.f);
    den += am;
  }
  out_tok[(size_t)t*CT_+ct] = num/den;
}

extern "C" void kernel_launch(void* const* d_in, const int* in_sizes, int n_in,
                              void* d_out, int out_size, void* d_ws, size_t ws_size,
                              hipStream_t stream) {
  (void)in_sizes; (void)n_in; (void)out_size; (void)ws_size;
  const float* ref_positions = (const float*)d_in[0];
  const float* ref_mask      = (const float*)d_in[1];
  const float* ref_charge    = (const float*)d_in[2];
  const float* atom_mask     = (const float*)d_in[3];
  const int*   ref_element   = (const int*)d_in[4];
  const int*   ref_chars     = (const int*)d_in[5];
  const int*   ref_uid       = (const int*)d_in[6];
  const int*   t2q           = (const int*)d_in[7];
  const int*   q2k           = (const int*)d_in[8];
  const int*   q2t           = (const int*)d_in[9];
  const float* w_ref_pos     = (const float*)d_in[10];
  const float* w_ref_mask    = (const float*)d_in[11];
  const float* w_ref_element = (const float*)d_in[12];
  const float* w_ref_charge  = (const float*)d_in[13];
  const float* w_ref_name    = (const float*)d_in[14];
  const float* w_s2p_row1    = (const float*)d_in[15];
  const float* w_s2p_col1    = (const float*)d_in[16];
  const float* w_pair_off1   = (const float*)d_in[17];
  const float* w_pair_dist1  = (const float*)d_in[18];
  const float* w_pair_valid  = (const float*)d_in[19];
  const float* w_mlp1        = (const float*)d_in[20];
  const float* w_mlp2        = (const float*)d_in[21];
  const float* w_mlp3        = (const float*)d_in[22];
  const float* wq            = (const float*)d_in[23];
  const float* wk            = (const float*)d_in[24];
  const float* wv            = (const float*)d_in[25];
  const float* wb            = (const float*)d_in[26];
  const float* wo            = (const float*)d_in[27];
  const float* w_proj        = (const float*)d_in[28];

  char* ws = (char*)d_ws;
  float* qsc     = (float*)(ws + 0);          // 9,437,184
  float* qmask   = (float*)(ws + 9437184);    //    73,728
  float* qrp     = (float*)(ws + 9732096);    //   221,184
  int*   quid    = (int*)  (ws + 9953280);    //    73,728
  float* krp     = (float*)(ws + 10027008);   //   884,736
  int*   kuid    = (int*)  (ws + 10911744);   //   294,912
  float* rowproj = (float*)(ws + 11206656);   // 1,179,648
  float* colproj = (float*)(ws + 12386304);   // 1,179,648
  float* Qp      = (float*)(ws + 13565952);   // 9,437,184
  float* Kp      = (float*)(ws + 23003136);   // 9,437,184
  float* Vp      = (float*)(ws + 32440320);   // 9,437,184
  float* O       = (float*)(ws + 41877504);   // 9,437,184
  float* qact    = (float*)(ws + 51314688);   // 9,437,184
  u16*   biasws  = (u16*)  (ws + 60751872);   // 18,874,368 -> 79,626,240 total

  float* out = (float*)d_out;   // fp32 outputs: reference dtype is float32
  float* out_tok   = out + 0;          // (768,384)        =   294,912
  float* out_skip  = out + 294912;     // (576,32,128)     = 2,359,296
  float* out_qmask = out + 2654208;    // (576,32)         =    18,432
  float* out_qsc   = out + 2672640;    // (576,32,128)     = 2,359,296
  float* out_kmask = out + 5031936;    // (576,128)        =    73,728
  float* out_ksc   = out + 5105664;    // (576,128,128)    = 9,437,184
  float* out_pair  = out + 14542848;   // (576,32,128,16)  = 37,748,736

  hipLaunchKernelGGL(n_qsc, dim3(SQ_), dim3(128), 0, stream,
      ref_positions, ref_mask, ref_charge, atom_mask, ref_element, ref_chars, ref_uid, t2q,
      w_ref_pos, w_ref_mask, w_ref_element, w_ref_charge, w_ref_name,
      qsc, qmask, qrp, quid, out_qsc, out_qmask);
  hipLaunchKernelGGL(n_keys, dim3(SK_), dim3(128), 0, stream,
      qsc, qmask, qrp, ref_uid, q2k, krp, kuid, out_ksc, out_kmask);
  hipLaunchKernelGGL(n_proj128, dim3(SQ_), dim3(128), 0, stream,
      qsc, wq, Qp, 0.17677669529663687f);   // 1/sqrt(32) baked into Q
  hipLaunchKernelGGL(n_proj128, dim3(SQ_), dim3(128), 0, stream,
      qsc, wk, Kp, 1.0f);
  hipLaunchKernelGGL(n_proj128, dim3(SQ_), dim3(128), 0, stream,
      qsc, wv, Vp, 1.0f);
  hipLaunchKernelGGL(n_proj16, dim3(SQ_/8), dim3(128), 0, stream,
      qsc, w_s2p_row1, rowproj);
  hipLaunchKernelGGL(n_proj16, dim3(SQ_/8), dim3(128), 0, stream,
      qsc, w_s2p_col1, colproj);
  hipLaunchKernelGGL(n_pair, dim3(SQ_), dim3(128), 0, stream,
      q2k, rowproj, colproj, qrp, quid, krp, kuid,
      w_mlp1, w_mlp2, w_mlp3, w_pair_off1, w_pair_dist1, w_pair_valid, wb,
      out_pair, biasws);
  hipLaunchKernelGGL(n_attn, dim3(SQ_*H_), dim3(64), 0, stream,
      Qp, Kp, Vp, qmask, biasws, q2k, O);
  hipLaunchKernelGGL(n_qact, dim3(SQ_), dim3(128), 0, stream,
      qsc, O, qmask, wo, qact, out_skip);
  hipLaunchKernelGGL(n_tok, dim3(T_), dim3(384), 0, stream,
      qact, q2t, atom_mask, w_proj, out_tok);
}